// Round 11
// baseline (172.956 us; speedup 1.0000x reference)
//
#include <hip/hip_runtime.h>

#define N_NODES 100000
#define N_EDGES 1600000
#define IN_F 256
#define OUT_F 64
#define NPAD 100096
#define NB 391            // node buckets of 256 nodes
#define NBLK 200          // partition blocks
#define CHUNK 8000        // edges per partition block (200*8000 = 1.6M exact)
#define MSIZE (2*NB*NBLK) // dst matrix then src matrix
#define SC_BLOCKS 612     // ceil(MSIZE/256)
#define CAP 12288         // LDS staging capacity per bucket

typedef __attribute__((ext_vector_type(8))) short short8v;
typedef __attribute__((ext_vector_type(4))) float f32x4;

__device__ __forceinline__ unsigned short f2bf(float f) {
    unsigned u = __builtin_bit_cast(unsigned, f);
    return (unsigned short)((u + 0x7FFFu + ((u >> 16) & 1u)) >> 16);
}
__device__ __forceinline__ float bf2f(unsigned s) {
    return __builtin_bit_cast(float, s << 16);
}
__device__ __forceinline__ void split_bf16(float f, unsigned short& hi, unsigned short& lo) {
    unsigned u = __builtin_bit_cast(unsigned, f);
    unsigned r = (u + 0x7FFFu + ((u >> 16) & 1u)) >> 16;
    hi = (unsigned short)r;
    float hif = __builtin_bit_cast(float, r << 16);
    float l = f - hif;
    unsigned ul = __builtin_bit_cast(unsigned, l);
    unsigned rl = (ul + 0x7FFFu + ((ul >> 16) & 1u)) >> 16;
    lo = (unsigned short)rl;
}
__device__ __forceinline__ void split8(float4 x, float4 y, short8v& hi, short8v& lo) {
    float f[8] = {x.x, x.y, x.z, x.w, y.x, y.y, y.z, y.w};
    #pragma unroll
    for (int i = 0; i < 8; ++i) {
        unsigned short h, l;
        split_bf16(f[i], h, l);
        hi[i] = (short)h; lo[i] = (short)l;
    }
}

// --- per-block bucket histograms (dst and src), no global atomics ---
__global__ __launch_bounds__(256) void histA_kernel(const int* __restrict__ src,
                                                    const int* __restrict__ dst,
                                                    int* __restrict__ hist_g) {
    __shared__ int hD[NB], hS[NB];
    int b = blockIdx.x, t = threadIdx.x;
    for (int j = t; j < NB; j += 256) { hD[j] = 0; hS[j] = 0; }
    __syncthreads();
    int e0 = b * CHUNK;
    for (int e = e0 + t; e < e0 + CHUNK; e += 256) {
        atomicAdd(&hD[dst[e] >> 8], 1);
        atomicAdd(&hS[src[e] >> 8], 1);
    }
    __syncthreads();
    for (int j = t; j < NB; j += 256) {
        hist_g[j * NBLK + b] = hD[j];
        hist_g[NB * NBLK + j * NBLK + b] = hS[j];
    }
}

// --- exclusive scan of hist_g[MSIZE] (in-place), 3 kernels ---
__global__ __launch_bounds__(256) void scan1_kernel(int* __restrict__ data,
                                                    int* __restrict__ partials) {
    __shared__ int sm[256];
    int i = blockIdx.x * 256 + threadIdx.x;
    int v = (i < MSIZE) ? data[i] : 0;
    sm[threadIdx.x] = v;
    __syncthreads();
    int x = v;
    #pragma unroll
    for (int off = 1; off < 256; off <<= 1) {
        int tv = 0;
        if ((int)threadIdx.x >= off) tv = sm[threadIdx.x - off];
        __syncthreads();
        x += tv;
        sm[threadIdx.x] = x;
        __syncthreads();
    }
    if (i < MSIZE) data[i] = x - v;
    if (threadIdx.x == 255) partials[blockIdx.x] = x;
}

__global__ __launch_bounds__(1024) void scan2_kernel(int* __restrict__ partials) {
    __shared__ int sm[1024];
    int i = threadIdx.x;
    int v = (i < SC_BLOCKS) ? partials[i] : 0;
    sm[i] = v;
    __syncthreads();
    int x = v;
    #pragma unroll
    for (int off = 1; off < 1024; off <<= 1) {
        int tv = 0;
        if (i >= off) tv = sm[i - off];
        __syncthreads();
        x += tv;
        sm[i] = x;
        __syncthreads();
    }
    if (i < SC_BLOCKS) partials[i] = x - v;
}

__global__ __launch_bounds__(256) void scan3_kernel(int* __restrict__ data,
                                                    const int* __restrict__ partials,
                                                    int* __restrict__ base_d,
                                                    int* __restrict__ base_s) {
    int i = blockIdx.x * 256 + threadIdx.x;
    if (i < MSIZE) {
        int v = data[i] + partials[blockIdx.x];
        data[i] = v;
        if (i % NBLK == 0) {
            int q = i / NBLK;
            if (q < NB) base_d[q] = v;
            else        base_s[q - NB] = v - N_EDGES;
        }
    }
    if (i == 0) { base_d[NB] = N_EDGES; base_s[NB] = N_EDGES; }
}

// --- partition edges into dst-buckets (packed dlocal|src) and src keys into src-buckets ---
__global__ __launch_bounds__(256) void part_kernel(const int* __restrict__ src,
                                                   const int* __restrict__ dst,
                                                   const int* __restrict__ hist_g,
                                                   unsigned* __restrict__ edge_buf,
                                                   int* __restrict__ src_part) {
    __shared__ int curD[NB], curS[NB];
    int b = blockIdx.x, t = threadIdx.x;
    for (int j = t; j < NB; j += 256) {
        curD[j] = hist_g[j * NBLK + b];
        curS[j] = hist_g[NB * NBLK + j * NBLK + b] - N_EDGES;
    }
    __syncthreads();
    int e0 = b * CHUNK;
    for (int e = e0 + t; e < e0 + CHUNK; e += 256) {
        int s = src[e], d = dst[e];
        int pD = atomicAdd(&curD[d >> 8], 1);
        edge_buf[pD] = ((unsigned)(d & 255) << 17) | (unsigned)s;
        int pS = atomicAdd(&curS[s >> 8], 1);
        src_part[pS] = s;
    }
}

// --- per-bucket out-degree -> norm_out ---
__global__ __launch_bounds__(256) void normout_kernel(const int* __restrict__ src_part,
                                                      const int* __restrict__ base_s,
                                                      float* __restrict__ norm_out) {
    __shared__ int hist[256];
    int j = blockIdx.x, t = threadIdx.x;
    hist[t] = 0;
    __syncthreads();
    int b0 = base_s[j], b1 = base_s[j + 1];
    for (int e = b0 + t; e < b1; e += 256)
        atomicAdd(&hist[src_part[e] & 255], 1);
    __syncthreads();
    int node = j * 256 + t;
    if (node < N_NODES) {
        int d = hist[t]; if (d < 1) d = 1;
        norm_out[node] = rsqrtf((float)d);
    }
}

// --- per-bucket in-LDS counting sort -> dst-sorted CSR (in place), emits row_ptr ---
__global__ __launch_bounds__(256) void bucket_kernel(unsigned* __restrict__ edge_buf,
                                                     const int* __restrict__ base_d,
                                                     int* __restrict__ row_ptr) {
    __shared__ unsigned stage[CAP];
    __shared__ int hist[256];
    __shared__ int cur[256];
    int j = blockIdx.x, t = threadIdx.x;
    int b0 = base_d[j], b1 = base_d[j + 1];
    int cnt = b1 - b0;
    hist[t] = 0;
    __syncthreads();
    for (int i = t; i < cnt; i += 256) {
        unsigned p = edge_buf[b0 + i];
        stage[i] = p;
        atomicAdd(&hist[p >> 17], 1);
    }
    __syncthreads();
    int v = hist[t];
    cur[t] = v;
    __syncthreads();
    int x = v;
    #pragma unroll
    for (int off = 1; off < 256; off <<= 1) {
        int tv = (t >= off) ? cur[t - off] : 0;
        __syncthreads();
        x += tv;
        cur[t] = x;
        __syncthreads();
    }
    int excl = x - v;
    row_ptr[j * 256 + t] = b0 + excl;
    cur[t] = excl;
    __syncthreads();
    for (int i = t; i < cnt; i += 256) {
        unsigned p = stage[i];
        int pos = atomicAdd(&cur[p >> 17], 1);
        edge_buf[b0 + pos] = p & 0x1FFFFu;
    }
}

// --- one-shot W split into MFMA-native lane-ordered layout:
//     Wt3[ks4][cf][part][lane(l4*16+l15)][8 shorts]  (64 KB total)
__global__ __launch_bounds__(256) void wsplit_kernel(const float* __restrict__ W,
                                                     unsigned short* __restrict__ Wt3) {
    int i = blockIdx.x * 256 + threadIdx.x;   // 0..16383 over W[k][c]
    int k = i >> 6, c = i & 63;
    int ks4 = k >> 5, kin = k & 31, l4v = kin >> 3, kq = kin & 7;
    int cf  = c >> 4, l15v = c & 15;
    unsigned short hi, lo;
    split_bf16(W[i], hi, lo);
    size_t idx_hi = ((((size_t)ks4 * 4 + cf) * 2 + 0) * 64 + l4v * 16 + l15v) * 8 + kq;
    size_t idx_lo = ((((size_t)ks4 * 4 + cf) * 2 + 1) * 64 + l4v * 16 + l15v) * 8 + kq;
    Wt3[idx_hi] = hi;
    Wt3[idx_lo] = lo;
}

// --- MFMA GEMM: barrier-free per-wave DMA pipeline.
//     391 blocks x 4 consecutive 64-row tiles; wave w owns rows [16w,16w+16) of each
//     tile end-to-end (stages them itself, computes, stores) -> NO __syncthreads.
//     Units = K-halves (32KB), double-buffered; counted s_waitcnt vmcnt(8) keeps the
//     next unit's 8 DMAs in flight across the wait (never drain mid-pipeline).
__global__ __launch_bounds__(256) void gemm_kernel(const float* __restrict__ feat,
                                                   const unsigned short* __restrict__ Wt3,
                                                   const float* __restrict__ norm_out,
                                                   unsigned short* __restrict__ h) {
    __shared__ float As[2][64 * 128];   // two 32KB unit buffers (64 rows x 128 K-floats)
    const int tid  = threadIdx.x;
    const int wave = tid >> 6, lane = tid & 63;
    const int l15  = lane & 15, l4 = lane >> 4;
    const int tile0 = blockIdx.x * 4;
    const unsigned short* pB = Wt3 + (size_t)lane * 8;

    // hoist all norm_out loads before the DMA pipeline (keeps vmcnt counts clean)
    float nrm[4][4];
    #pragma unroll
    for (int i = 0; i < 4; ++i)
        #pragma unroll
        for (int r = 0; r < 4; ++r) {
            int row = (tile0 + i) * 64 + wave * 16 + l4 * 4 + r;
            nrm[i][r] = norm_out[row < N_NODES ? row : 0];
        }

    const int rr = wave * 16 + l15;   // local row of this lane's A fragment
    const int rs = rr & 7;            // XOR swizzle key (matches source pre-swizzle)

    auto stage = [&](int u) {
        const int tile = tile0 + (u >> 1), half = u & 1;
        float* buf = &As[u & 1][0];
        #pragma unroll
        for (int i = 0; i < 8; ++i) {
            int rloc = wave * 16 + 2 * i + (lane >> 5);
            int rowg = tile * 64 + rloc;
            if (rowg >= N_NODES) rowg = N_NODES - 1;   // clamp; results discarded
            int chunk = (lane & 31) ^ (rloc & 7);       // pre-swizzled global source
            const float* gsrc = feat + (size_t)rowg * IN_F + half * 128 + (chunk << 2);
            float* ldst = buf + (wave * 16 + 2 * i) * 128;  // wave-uniform, lane*16B linear
            __builtin_amdgcn_global_load_lds(
                (const __attribute__((address_space(1))) void*)gsrc,
                (__attribute__((address_space(3))) void*)ldst, 16, 0, 0);
        }
    };

    stage(0);
    f32x4 acc[4];
    #pragma unroll
    for (int i = 0; i < 4; ++i) {
        #pragma unroll
        for (int half = 0; half < 2; ++half) {
            const int u = i * 2 + half;
            if (u + 1 < 8) {
                stage(u + 1);
                asm volatile("s_waitcnt vmcnt(8)" ::: "memory");   // unit u done; u+1 in flight
            } else {
                asm volatile("s_waitcnt vmcnt(0)" ::: "memory");   // final unit
            }
            __builtin_amdgcn_sched_barrier(0);
            if (half == 0) {
                #pragma unroll
                for (int cf = 0; cf < 4; ++cf) acc[cf] = (f32x4){0.f, 0.f, 0.f, 0.f};
            }
            const float* buf = &As[u & 1][0];
            #pragma unroll
            for (int step = 0; step < 4; ++step) {
                const int ks4 = half * 4 + step;
                short8v bh[4], bl[4];
                #pragma unroll
                for (int cf = 0; cf < 4; ++cf) {
                    bh[cf] = *(const short8v*)(pB + ((size_t)(ks4 * 4 + cf) * 2 + 0) * 512);
                    bl[cf] = *(const short8v*)(pB + ((size_t)(ks4 * 4 + cf) * 2 + 1) * 512);
                }
                const int c = step * 8 + l4 * 2;
                float4 fx = *(const float4*)&buf[rr * 128 + (((c + 0) ^ rs) << 2)];
                float4 fy = *(const float4*)&buf[rr * 128 + (((c + 1) ^ rs) << 2)];
                short8v a_hi, a_lo;
                split8(fx, fy, a_hi, a_lo);
                #pragma unroll
                for (int cf = 0; cf < 4; ++cf) {
                    acc[cf] = __builtin_amdgcn_mfma_f32_16x16x32_bf16(a_hi, bh[cf], acc[cf], 0, 0, 0);
                    acc[cf] = __builtin_amdgcn_mfma_f32_16x16x32_bf16(a_hi, bl[cf], acc[cf], 0, 0, 0);
                    acc[cf] = __builtin_amdgcn_mfma_f32_16x16x32_bf16(a_lo, bh[cf], acc[cf], 0, 0, 0);
                }
            }
            if (half == 1) {
                const int tile = tile0 + i;
                #pragma unroll
                for (int r = 0; r < 4; ++r) {
                    int row = tile * 64 + wave * 16 + l4 * 4 + r;
                    if (row < N_NODES) {
                        float s = nrm[i][r];
                        #pragma unroll
                        for (int cf = 0; cf < 4; ++cf)
                            h[(size_t)row * OUT_F + cf * 16 + l15] = f2bf(acc[cf][r] * s);
                    }
                }
            }
        }
    }
}

// --- aggregate: one wave per dst node. Lanes 0-31 <-> edge e, 32-63 <-> edge e+1;
//     each lane loads bf16x2 (features 2*sl, 2*sl+1). Fused norm+bias+relu. ---
__global__ __launch_bounds__(256) void agg_kernel(const int* __restrict__ row_ptr,
                                                  const unsigned* __restrict__ edge_src,
                                                  const unsigned short* __restrict__ h,
                                                  const float* __restrict__ bias,
                                                  float* __restrict__ out) {
    int wid  = (blockIdx.x * 256 + threadIdx.x) >> 6;
    int lane = threadIdx.x & 63;
    if (wid >= N_NODES) return;
    int half = lane >> 5;
    int sl   = lane & 31;
    int start = row_ptr[wid];
    int end   = row_ptr[wid + 1];
    int deg   = end - start;

    float ax0 = 0.f, ay0 = 0.f, ax1 = 0.f, ay1 = 0.f;
    int e = start + half;
    for (; e + 7 < end + half; e += 8) {
        #pragma unroll
        for (int k = 0; k < 4; ++k) {
            int s = (int)edge_src[e + 2 * k];
            unsigned wv = *(const unsigned*)&h[(size_t)s * OUT_F + sl * 2];
            if (k & 1) { ax1 += bf2f(wv & 0xFFFFu); ay1 += bf2f(wv >> 16); }
            else       { ax0 += bf2f(wv & 0xFFFFu); ay0 += bf2f(wv >> 16); }
        }
    }
    for (; e < end; e += 2) {
        int s = (int)edge_src[e];
        unsigned wv = *(const unsigned*)&h[(size_t)s * OUT_F + sl * 2];
        ax0 += bf2f(wv & 0xFFFFu); ay0 += bf2f(wv >> 16);
    }
    float ax = ax0 + ax1, ay = ay0 + ay1;
    ax += __shfl_xor(ax, 32);
    ay += __shfl_xor(ay, 32);

    if (half == 0) {
        int dc = deg < 1 ? 1 : deg;
        float nrm = rsqrtf((float)dc);
        float2 r;
        r.x = fmaxf(ax * nrm + bias[sl * 2 + 0], 0.f);
        r.y = fmaxf(ay * nrm + bias[sl * 2 + 1], 0.f);
        *(float2*)&out[(size_t)wid * OUT_F + sl * 2] = r;
    }
}

extern "C" void kernel_launch(void* const* d_in, const int* in_sizes, int n_in,
                              void* d_out, int out_size, void* d_ws, size_t ws_size,
                              hipStream_t stream) {
    const float* feat = (const float*)d_in[0];
    const float* W    = (const float*)d_in[1];
    const float* bias = (const float*)d_in[2];
    const int*   src  = (const int*)d_in[3];
    const int*   dst  = (const int*)d_in[4];
    float* out = (float*)d_out;

    char* w = (char*)d_ws;
    size_t off = 0;
    auto take = [&](size_t bytes) { char* p = w + off; off += (bytes + 255) & ~(size_t)255; return p; };

    int*            hist_g   = (int*)take((size_t)MSIZE * 4);
    int*            partials = (int*)take((size_t)SC_BLOCKS * 4);
    int*            base_d   = (int*)take((size_t)(NB + 1) * 4);
    int*            base_s   = (int*)take((size_t)(NB + 1) * 4);
    float*          norm_out = (float*)take((size_t)NPAD * 4);
    int*            row_ptr  = (int*)take((size_t)(NPAD + 64) * 4);
    unsigned short* Wt3      = (unsigned short*)take((size_t)IN_F * OUT_F * 2 * 2);  // 64 KB
    unsigned*       edge_buf = (unsigned*)take((size_t)N_EDGES * 4);
    unsigned short* h        = (unsigned short*)take((size_t)N_NODES * OUT_F * 4); // slack ok
    int*            src_part = (int*)h;  // alias: consumed by normout before gemm writes h

    wsplit_kernel<<<(IN_F * OUT_F) / 256, 256, 0, stream>>>(W, Wt3);
    histA_kernel<<<NBLK, 256, 0, stream>>>(src, dst, hist_g);
    scan1_kernel<<<SC_BLOCKS, 256, 0, stream>>>(hist_g, partials);
    scan2_kernel<<<1, 1024, 0, stream>>>(partials);
    scan3_kernel<<<SC_BLOCKS, 256, 0, stream>>>(hist_g, partials, base_d, base_s);
    part_kernel<<<NBLK, 256, 0, stream>>>(src, dst, hist_g, edge_buf, src_part);
    normout_kernel<<<NB, 256, 0, stream>>>(src_part, base_s, norm_out);
    bucket_kernel<<<NB, 256, 0, stream>>>(edge_buf, base_d, row_ptr);
    gemm_kernel<<<NB, 256, 0, stream>>>(feat, Wt3, norm_out, h);   // 391 blocks x 4 tiles
    agg_kernel<<<(N_NODES * 64 + 255) / 256, 256, 0, stream>>>(row_ptr, edge_buf, h, bias, out);
}

// Round 12
// 152.945 us; speedup vs baseline: 1.1308x; 1.1308x over previous
//
#include <hip/hip_runtime.h>

#define N_NODES 100000
#define N_EDGES 1600000
#define IN_F 256
#define OUT_F 64
#define NPAD 100096
#define NB 391            // node buckets of 256 nodes
#define NBLK 200          // partition blocks
#define CHUNK 8000        // edges per partition block (200*8000 = 1.6M exact)
#define MSIZE (2*NB*NBLK) // dst matrix then src matrix
#define SC_BLOCKS 612     // ceil(MSIZE/256)
#define CAP 12288         // LDS staging capacity per bucket

typedef __attribute__((ext_vector_type(8))) _Float16 half8v;
typedef __attribute__((ext_vector_type(4))) float f32x4;

__device__ __forceinline__ unsigned short f2bf(float f) {
    unsigned u = __builtin_bit_cast(unsigned, f);
    return (unsigned short)((u + 0x7FFFu + ((u >> 16) & 1u)) >> 16);
}
__device__ __forceinline__ float bf2f(unsigned s) {
    return __builtin_bit_cast(float, s << 16);
}
__device__ __forceinline__ half8v cvt8(float4 x, float4 y) {
    half8v r;
    r[0] = (_Float16)x.x; r[1] = (_Float16)x.y; r[2] = (_Float16)x.z; r[3] = (_Float16)x.w;
    r[4] = (_Float16)y.x; r[5] = (_Float16)y.y; r[6] = (_Float16)y.z; r[7] = (_Float16)y.w;
    return r;
}

// --- per-block bucket histograms (dst and src), no global atomics ---
__global__ __launch_bounds__(256) void histA_kernel(const int* __restrict__ src,
                                                    const int* __restrict__ dst,
                                                    int* __restrict__ hist_g) {
    __shared__ int hD[NB], hS[NB];
    int b = blockIdx.x, t = threadIdx.x;
    for (int j = t; j < NB; j += 256) { hD[j] = 0; hS[j] = 0; }
    __syncthreads();
    int e0 = b * CHUNK;
    for (int e = e0 + t; e < e0 + CHUNK; e += 256) {
        atomicAdd(&hD[dst[e] >> 8], 1);
        atomicAdd(&hS[src[e] >> 8], 1);
    }
    __syncthreads();
    for (int j = t; j < NB; j += 256) {
        hist_g[j * NBLK + b] = hD[j];
        hist_g[NB * NBLK + j * NBLK + b] = hS[j];
    }
}

// --- exclusive scan of hist_g[MSIZE] (in-place), 3 kernels ---
__global__ __launch_bounds__(256) void scan1_kernel(int* __restrict__ data,
                                                    int* __restrict__ partials) {
    __shared__ int sm[256];
    int i = blockIdx.x * 256 + threadIdx.x;
    int v = (i < MSIZE) ? data[i] : 0;
    sm[threadIdx.x] = v;
    __syncthreads();
    int x = v;
    #pragma unroll
    for (int off = 1; off < 256; off <<= 1) {
        int tv = 0;
        if ((int)threadIdx.x >= off) tv = sm[threadIdx.x - off];
        __syncthreads();
        x += tv;
        sm[threadIdx.x] = x;
        __syncthreads();
    }
    if (i < MSIZE) data[i] = x - v;
    if (threadIdx.x == 255) partials[blockIdx.x] = x;
}

__global__ __launch_bounds__(1024) void scan2_kernel(int* __restrict__ partials) {
    __shared__ int sm[1024];
    int i = threadIdx.x;
    int v = (i < SC_BLOCKS) ? partials[i] : 0;
    sm[i] = v;
    __syncthreads();
    int x = v;
    #pragma unroll
    for (int off = 1; off < 1024; off <<= 1) {
        int tv = 0;
        if (i >= off) tv = sm[i - off];
        __syncthreads();
        x += tv;
        sm[i] = x;
        __syncthreads();
    }
    if (i < SC_BLOCKS) partials[i] = x - v;
}

__global__ __launch_bounds__(256) void scan3_kernel(int* __restrict__ data,
                                                    const int* __restrict__ partials,
                                                    int* __restrict__ base_d,
                                                    int* __restrict__ base_s) {
    int i = blockIdx.x * 256 + threadIdx.x;
    if (i < MSIZE) {
        int v = data[i] + partials[blockIdx.x];
        data[i] = v;
        if (i % NBLK == 0) {
            int q = i / NBLK;
            if (q < NB) base_d[q] = v;
            else        base_s[q - NB] = v - N_EDGES;
        }
    }
    if (i == 0) { base_d[NB] = N_EDGES; base_s[NB] = N_EDGES; }
}

// --- partition edges into dst-buckets (packed dlocal|src) and src keys into src-buckets ---
__global__ __launch_bounds__(256) void part_kernel(const int* __restrict__ src,
                                                   const int* __restrict__ dst,
                                                   const int* __restrict__ hist_g,
                                                   unsigned* __restrict__ edge_buf,
                                                   int* __restrict__ src_part) {
    __shared__ int curD[NB], curS[NB];
    int b = blockIdx.x, t = threadIdx.x;
    for (int j = t; j < NB; j += 256) {
        curD[j] = hist_g[j * NBLK + b];
        curS[j] = hist_g[NB * NBLK + j * NBLK + b] - N_EDGES;
    }
    __syncthreads();
    int e0 = b * CHUNK;
    for (int e = e0 + t; e < e0 + CHUNK; e += 256) {
        int s = src[e], d = dst[e];
        int pD = atomicAdd(&curD[d >> 8], 1);
        edge_buf[pD] = ((unsigned)(d & 255) << 17) | (unsigned)s;
        int pS = atomicAdd(&curS[s >> 8], 1);
        src_part[pS] = s;
    }
}

// --- per-bucket out-degree -> norm_out ---
__global__ __launch_bounds__(256) void normout_kernel(const int* __restrict__ src_part,
                                                      const int* __restrict__ base_s,
                                                      float* __restrict__ norm_out) {
    __shared__ int hist[256];
    int j = blockIdx.x, t = threadIdx.x;
    hist[t] = 0;
    __syncthreads();
    int b0 = base_s[j], b1 = base_s[j + 1];
    for (int e = b0 + t; e < b1; e += 256)
        atomicAdd(&hist[src_part[e] & 255], 1);
    __syncthreads();
    int node = j * 256 + t;
    if (node < N_NODES) {
        int d = hist[t]; if (d < 1) d = 1;
        norm_out[node] = rsqrtf((float)d);
    }
}

// --- per-bucket in-LDS counting sort -> dst-sorted CSR (in place), emits row_ptr ---
__global__ __launch_bounds__(256) void bucket_kernel(unsigned* __restrict__ edge_buf,
                                                     const int* __restrict__ base_d,
                                                     int* __restrict__ row_ptr) {
    __shared__ unsigned stage[CAP];
    __shared__ int hist[256];
    __shared__ int cur[256];
    int j = blockIdx.x, t = threadIdx.x;
    int b0 = base_d[j], b1 = base_d[j + 1];
    int cnt = b1 - b0;
    hist[t] = 0;
    __syncthreads();
    for (int i = t; i < cnt; i += 256) {
        unsigned p = edge_buf[b0 + i];
        stage[i] = p;
        atomicAdd(&hist[p >> 17], 1);
    }
    __syncthreads();
    int v = hist[t];
    cur[t] = v;
    __syncthreads();
    int x = v;
    #pragma unroll
    for (int off = 1; off < 256; off <<= 1) {
        int tv = (t >= off) ? cur[t - off] : 0;
        __syncthreads();
        x += tv;
        cur[t] = x;
        __syncthreads();
    }
    int excl = x - v;
    row_ptr[j * 256 + t] = b0 + excl;
    cur[t] = excl;
    __syncthreads();
    for (int i = t; i < cnt; i += 256) {
        unsigned p = stage[i];
        int pos = atomicAdd(&cur[p >> 17], 1);
        edge_buf[b0 + pos] = p & 0x1FFFFu;
    }
}

// --- one-shot W -> fp16, MFMA-native lane order:
//     Wt2[(ks4*4+cf)*64 + lane][8 halfs]  (32 KB total)
__global__ __launch_bounds__(256) void wsplit_kernel(const float* __restrict__ W,
                                                     _Float16* __restrict__ Wt2) {
    int i = blockIdx.x * 256 + threadIdx.x;   // 0..16383 over W[k][c]
    int k = i >> 6, c = i & 63;
    int ks4 = k >> 5, kin = k & 31, l4v = kin >> 3, kq = kin & 7;
    int cf  = c >> 4, l15v = c & 15;
    size_t idx = (((size_t)(ks4 * 4 + cf) * 64) + l4v * 16 + l15v) * 8 + kq;
    Wt2[idx] = (_Float16)W[i];
}

// --- MFMA GEMM (fp16 single-MFMA): h[r][c] = (sum_k feat[r][k]*W[k][c]) * norm_out[r].
//     B staged ONCE per block into LDS (32 KB, global_load_lds) -> K-loop has no
//     global B traffic.  32 rows/wave, 128-row block tile, 782 blocks.
__global__ __launch_bounds__(256) void gemm_kernel(const float* __restrict__ feat,
                                                   const _Float16* __restrict__ Wt2,
                                                   const float* __restrict__ norm_out,
                                                   unsigned short* __restrict__ h) {
    __shared__ _Float16 Bs[16384];   // 32 KB, same lane-ordered layout as Wt2
    const int tid  = threadIdx.x;
    const int wave = tid >> 6, lane = tid & 63;
    const int l15  = lane & 15, l4 = lane >> 4;
    const int rw0  = blockIdx.x * 128 + wave * 32;

    // stage the whole B panel: 32 wave-instructions x 1KB contiguous
    #pragma unroll
    for (int i = 0; i < 8; ++i) {
        const int fr = i * 4 + wave;                  // fragment-row 0..31
        const _Float16* gsrc = Wt2 + ((size_t)fr * 64 + lane) * 8;
        _Float16* ldst = &Bs[(size_t)fr * 64 * 8];    // wave-uniform base, lane*16B linear
        __builtin_amdgcn_global_load_lds(
            (const __attribute__((address_space(1))) void*)gsrc,
            (__attribute__((address_space(3))) void*)ldst, 16, 0, 0);
    }

    int r0 = rw0 + l15;
    int r1 = r0 + 16;
    int r0c = r0 < N_NODES ? r0 : 0;   // clamp OOB reads; results discarded on store
    int r1c = r1 < N_NODES ? r1 : 0;
    const float* pA0 = feat + (size_t)r0c * IN_F + l4 * 8;
    const float* pA1 = feat + (size_t)r1c * IN_F + l4 * 8;

    f32x4 acc[2][4];
    #pragma unroll
    for (int rf = 0; rf < 2; ++rf)
        #pragma unroll
        for (int cf = 0; cf < 4; ++cf)
            acc[rf][cf] = (f32x4){0.f, 0.f, 0.f, 0.f};

    // A prefetch for step 0
    float4 nx0 = *(const float4*)(pA0);
    float4 ny0 = *(const float4*)(pA0 + 4);
    float4 nx1 = *(const float4*)(pA1);
    float4 ny1 = *(const float4*)(pA1 + 4);

    __syncthreads();   // B panel ready

    #pragma unroll
    for (int ks4 = 0; ks4 < 8; ++ks4) {
        float4 cx0 = nx0, cy0 = ny0, cx1 = nx1, cy1 = ny1;
        if (ks4 < 7) {
            nx0 = *(const float4*)(pA0 + 32 * (ks4 + 1));
            ny0 = *(const float4*)(pA0 + 32 * (ks4 + 1) + 4);
            nx1 = *(const float4*)(pA1 + 32 * (ks4 + 1));
            ny1 = *(const float4*)(pA1 + 32 * (ks4 + 1) + 4);
        }
        half8v bfr[4];
        #pragma unroll
        for (int cf = 0; cf < 4; ++cf)
            bfr[cf] = *(const half8v*)&Bs[(((size_t)(ks4 * 4 + cf) * 64) + lane) * 8];
        half8v a0 = cvt8(cx0, cy0);
        half8v a1 = cvt8(cx1, cy1);
        #pragma unroll
        for (int cf = 0; cf < 4; ++cf) {
            acc[0][cf] = __builtin_amdgcn_mfma_f32_16x16x32_f16(a0, bfr[cf], acc[0][cf], 0, 0, 0);
            acc[1][cf] = __builtin_amdgcn_mfma_f32_16x16x32_f16(a1, bfr[cf], acc[1][cf], 0, 0, 0);
        }
    }

    // epilogue: scale by norm_out, store h as bf16.  C/D map: col=l15, row=l4*4+r.
    #pragma unroll
    for (int rf = 0; rf < 2; ++rf) {
        #pragma unroll
        for (int r = 0; r < 4; ++r) {
            int row = rw0 + rf * 16 + l4 * 4 + r;
            if (row < N_NODES) {
                float s = norm_out[row];
                #pragma unroll
                for (int cf = 0; cf < 4; ++cf)
                    h[(size_t)row * OUT_F + cf * 16 + l15] = f2bf(acc[rf][cf][r] * s);
            }
        }
    }
}

// --- aggregate: one wave per dst node. Lanes 0-31 <-> edge e, 32-63 <-> edge e+1;
//     each lane loads bf16x2 (features 2*sl, 2*sl+1). Fused norm+bias+relu. ---
__global__ __launch_bounds__(256) void agg_kernel(const int* __restrict__ row_ptr,
                                                  const unsigned* __restrict__ edge_src,
                                                  const unsigned short* __restrict__ h,
                                                  const float* __restrict__ bias,
                                                  float* __restrict__ out) {
    int wid  = (blockIdx.x * 256 + threadIdx.x) >> 6;
    int lane = threadIdx.x & 63;
    if (wid >= N_NODES) return;
    int half = lane >> 5;
    int sl   = lane & 31;
    int start = row_ptr[wid];
    int end   = row_ptr[wid + 1];
    int deg   = end - start;

    float ax0 = 0.f, ay0 = 0.f, ax1 = 0.f, ay1 = 0.f;
    int e = start + half;
    for (; e + 7 < end + half; e += 8) {
        #pragma unroll
        for (int k = 0; k < 4; ++k) {
            int s = (int)edge_src[e + 2 * k];
            unsigned wv = *(const unsigned*)&h[(size_t)s * OUT_F + sl * 2];
            if (k & 1) { ax1 += bf2f(wv & 0xFFFFu); ay1 += bf2f(wv >> 16); }
            else       { ax0 += bf2f(wv & 0xFFFFu); ay0 += bf2f(wv >> 16); }
        }
    }
    for (; e < end; e += 2) {
        int s = (int)edge_src[e];
        unsigned wv = *(const unsigned*)&h[(size_t)s * OUT_F + sl * 2];
        ax0 += bf2f(wv & 0xFFFFu); ay0 += bf2f(wv >> 16);
    }
    float ax = ax0 + ax1, ay = ay0 + ay1;
    ax += __shfl_xor(ax, 32);
    ay += __shfl_xor(ay, 32);

    if (half == 0) {
        int dc = deg < 1 ? 1 : deg;
        float nrm = rsqrtf((float)dc);
        float2 r;
        r.x = fmaxf(ax * nrm + bias[sl * 2 + 0], 0.f);
        r.y = fmaxf(ay * nrm + bias[sl * 2 + 1], 0.f);
        *(float2*)&out[(size_t)wid * OUT_F + sl * 2] = r;
    }
}

extern "C" void kernel_launch(void* const* d_in, const int* in_sizes, int n_in,
                              void* d_out, int out_size, void* d_ws, size_t ws_size,
                              hipStream_t stream) {
    const float* feat = (const float*)d_in[0];
    const float* W    = (const float*)d_in[1];
    const float* bias = (const float*)d_in[2];
    const int*   src  = (const int*)d_in[3];
    const int*   dst  = (const int*)d_in[4];
    float* out = (float*)d_out;

    char* w = (char*)d_ws;
    size_t off = 0;
    auto take = [&](size_t bytes) { char* p = w + off; off += (bytes + 255) & ~(size_t)255; return p; };

    int*            hist_g   = (int*)take((size_t)MSIZE * 4);
    int*            partials = (int*)take((size_t)SC_BLOCKS * 4);
    int*            base_d   = (int*)take((size_t)(NB + 1) * 4);
    int*            base_s   = (int*)take((size_t)(NB + 1) * 4);
    float*          norm_out = (float*)take((size_t)NPAD * 4);
    int*            row_ptr  = (int*)take((size_t)(NPAD + 64) * 4);
    _Float16*       Wt2      = (_Float16*)take((size_t)IN_F * OUT_F * 2);   // 32 KB
    unsigned*       edge_buf = (unsigned*)take((size_t)N_EDGES * 4);
    unsigned short* h        = (unsigned short*)take((size_t)N_NODES * OUT_F * 4); // slack ok
    int*            src_part = (int*)h;  // alias: consumed by normout before gemm writes h

    wsplit_kernel<<<(IN_F * OUT_F) / 256, 256, 0, stream>>>(W, Wt2);
    histA_kernel<<<NBLK, 256, 0, stream>>>(src, dst, hist_g);
    scan1_kernel<<<SC_BLOCKS, 256, 0, stream>>>(hist_g, partials);
    scan2_kernel<<<1, 1024, 0, stream>>>(partials);
    scan3_kernel<<<SC_BLOCKS, 256, 0, stream>>>(hist_g, partials, base_d, base_s);
    part_kernel<<<NBLK, 256, 0, stream>>>(src, dst, hist_g, edge_buf, src_part);
    normout_kernel<<<NB, 256, 0, stream>>>(src_part, base_s, norm_out);
    bucket_kernel<<<NB, 256, 0, stream>>>(edge_buf, base_d, row_ptr);
    gemm_kernel<<<(NPAD / 128), 256, 0, stream>>>(feat, Wt2, norm_out, h);
    agg_kernel<<<(N_NODES * 64 + 255) / 256, 256, 0, stream>>>(row_ptr, edge_buf, h, bias, out);
}